// Round 6
// baseline (1014.464 us; speedup 1.0000x reference)
//
#include <hip/hip_runtime.h>

// VectorQuantizer: x [32768, 256] fp32, codebook [1024, 256] fp32.
// Harness reference recomputes in float32 (R3: absmax==0 with fp32-replica):
//   d[n,k] = fl( fl( ||x_n||^2 - 2*dot(x_n,c_k) ) + ||c_k||^2 )  all fp32
//   idx = np.argmin (first-index ties), out = codebook[idx]
// Replica invariants (DO NOT BREAK):
//  - dot: single sequential fp32 FMA chain per (n,k), d ascending.
//  - q = (S - 2*acc) + cn : two fp32 roundings in this order.
//  - S: fp32 squares, fp64-accumulated (order-invariant, R3-proven), 1 rounding.
//  - k ascending within wave + strict < ; cross-wave merge tie-breaks on index.
//
// R6 structure (R5 post-mortem: LDS pipe was 3x oversubscribed -- ds_read_b128
// ~12cyc/CU shared by all waves; small reg tiles lose):
//  - wave = 64 lanes = 64 distinct x-rows, SAME k for all lanes ->
//    b[k][d] is wave-uniform -> s_load (scalar cache) + SGPR FMA operand:
//    b costs ZERO LDS and ZERO vector-L1.
//  - a from LDS x-tile: 1 ds_read_b128 per dd feeds 8 k x 4 d = 32 FMAs.
//    LDS demand = 0.75x FMA demand at 16 waves/CU.
//  - block = 512 thr = 8 waves share one 64-row tile (66.5 KB); wave w owns
//    k in [128w, 128w+128). Grid 512 -> 2 blocks/CU = 16 waves/CU.
//  - lane-row reads at stride 260 = 4 mod 32: lanes 0..7 tile all 32 banks,
//    conflict-free b128.

#define D         256
#define K_TOTAL   1024
#define N_ROWS    32768
#define TM        64          // rows per block (= per wave, all waves same rows)
#define XS_STRIDE 260         // 256+4: rows 16B-aligned, bank-stride 4 mod 32

// ---------------- kernel 1: codebook squared norms ----------------
__global__ void cnorm_kernel(const float* __restrict__ cb, float* __restrict__ cnorm) {
    const int wave = threadIdx.x >> 6;
    const int lane = threadIdx.x & 63;
    const int k    = blockIdx.x * 4 + wave;       // 0..1023
    float4 v = *(const float4*)(cb + (size_t)k * D + lane * 4);
    float sx = v.x * v.x, sy = v.y * v.y, sz = v.z * v.z, sw = v.w * v.w;
    double s = (double)sx + (double)sy + (double)sz + (double)sw;
    #pragma unroll
    for (int off = 32; off > 0; off >>= 1)
        s += __shfl_down(s, off, 64);
    if (lane == 0) cnorm[k] = (float)s;
}

// ---------------- kernel 2: fused distance + argmin + gather ----------------
__global__ __launch_bounds__(512, 4)
void vq_kernel(const float* __restrict__ x, const float* __restrict__ cb,
               const float* __restrict__ cnorm, float* __restrict__ out) {
    __shared__ float  xs[TM * XS_STRIDE];   // 66560 B x-tile [64 n][256 d]
    __shared__ double sred[TM][8];          // 4 KB row-norm partials

    const int tid  = threadIdx.x;
    const int lane = tid & 63;              // row within tile (per-lane row)
    const int wv   = tid >> 6;              // 0..7: k-range owner
    const int n0   = blockIdx.x * TM;

    // ---- stage x-tile once (coalesced 16B loads) ----
    #pragma unroll
    for (int r = 0; r < 8; ++r) {
        const int idx  = tid + 512 * r;     // float4 index 0..4095
        const int row  = idx >> 6;
        const int col4 = idx & 63;
        float4 v = *(const float4*)(x + (size_t)(n0 + row) * D + col4 * 4);
        *(float4*)(xs + row * XS_STRIDE + col4 * 4) = v;
    }
    __syncthreads();

    // ---- row norms from LDS tile: fp32 squares, fp64 partials (8 thr/row) ----
    {
        const int r = tid >> 3, seg = tid & 7;
        const float* p = xs + r * XS_STRIDE + seg * 32;
        double s = 0.0;
        #pragma unroll
        for (int d = 0; d < 32; d += 4) {
            float4 v = *(const float4*)(p + d);
            float a0 = v.x * v.x, a1 = v.y * v.y, a2 = v.z * v.z, a3 = v.w * v.w;
            s += (double)a0 + (double)a1 + (double)a2 + (double)a3;
        }
        sred[r][seg] = s;
    }
    __syncthreads();

    float S;
    {
        double s = 0.0;
        #pragma unroll
        for (int t = 0; t < 8; ++t) s += sred[lane][t];
        S = (float)s;                       // single fp64->fp32 rounding
    }

    const float* arow = xs + lane * XS_STRIDE;
    float runmin = 1e30f;
    int   runidx = 0;

    // ---- K loop: wave-uniform k -> b via scalar loads (SGPR FMA operands) ----
    const int kbase = wv * 128;
    for (int kg = 0; kg < 16; ++kg) {
        const int k0 = kbase + kg * 8;      // ascending k across kg
        float acc[8];
        #pragma unroll
        for (int j = 0; j < 8; ++j) acc[j] = 0.f;

        // Sequential fp32 FMA chain per (row, k), d ascending — fp32 replica.
        #pragma unroll 2
        for (int dd = 0; dd < D; dd += 4) {
            const float4 a = *(const float4*)(arow + dd);     // ds_read_b128
            #pragma unroll
            for (int j = 0; j < 8; ++j) {
                const float4 b = *(const float4*)(cb + (size_t)(k0 + j) * D + dd); // s_load
                acc[j] += a.x * b.x;
                acc[j] += a.y * b.y;
                acc[j] += a.z * b.z;
                acc[j] += a.w * b.w;
            }
        }

        // q = (S - 2*acc) + cn, two fp32 roundings; ascending k, strict <
        #pragma unroll
        for (int j = 0; j < 8; ++j) {
            const float cn = cnorm[k0 + j];
            const float t = S - 2.0f * acc[j];
            const float q = t + cn;
            if (q < runmin) { runmin = q; runidx = k0 + j; }
        }
    }

    // ---- cross-wave argmin merge (8 candidates/row), overlaid into dead xs ----
    __syncthreads();                        // all K-loop xs readers done
    float* red_val = xs;                    // [8][64]
    int*   red_idx = (int*)(xs + 512);      // [8][64]
    int*   best    = (int*)(xs + 1024);     // [64]
    red_val[wv * 64 + lane] = runmin;
    red_idx[wv * 64 + lane] = runidx;
    __syncthreads();
    if (tid < TM) {
        float bv = red_val[tid];
        int   bi = red_idx[tid];
        #pragma unroll
        for (int w = 1; w < 8; ++w) {       // ascending wave = ascending k-range
            const float v = red_val[w * 64 + tid];
            const int  ix = red_idx[w * 64 + tid];
            if (v < bv || (v == bv && ix < bi)) { bv = v; bi = ix; }
        }
        best[tid] = bi;
    }
    __syncthreads();

    // ---- gather winning codebook rows -> out (wave covers 1 row: uniform k) ----
    #pragma unroll
    for (int r = 0; r < 8; ++r) {
        const int idx  = tid + 512 * r;
        const int row  = idx >> 6;
        const int col4 = idx & 63;
        const int k    = best[row];
        float4 v = *(const float4*)(cb + (size_t)k * D + col4 * 4);
        *(float4*)(out + (size_t)(n0 + row) * D + col4 * 4) = v;
    }
}

extern "C" void kernel_launch(void* const* d_in, const int* in_sizes, int n_in,
                              void* d_out, int out_size, void* d_ws, size_t ws_size,
                              hipStream_t stream) {
    const float* x  = (const float*)d_in[0];   // [32768, 256]
    const float* cb = (const float*)d_in[1];   // [1024, 256]
    float* out   = (float*)d_out;              // [32768, 256]
    float* cnorm = (float*)d_ws;               // 1024 fp32 scratch

    const int N = in_sizes[0] / D;             // 32768
    cnorm_kernel<<<K_TOTAL / 4, 256, 0, stream>>>(cb, cnorm);
    vq_kernel<<<N / TM, 512, 0, stream>>>(x, cb, cnorm, out);
}

// Round 7
// 1009.480 us; speedup vs baseline: 1.0049x; 1.0049x over previous
//
#include <hip/hip_runtime.h>

// VectorQuantizer: x [32768, 256] fp32, codebook [1024, 256] fp32.
// Harness reference recomputes in float32 (R3: absmax==0 with fp32-replica):
//   d[n,k] = fl( fl( ||x_n||^2 - 2*dot(x_n,c_k) ) + ||c_k||^2 )  all fp32
//   idx = np.argmin (first-index ties), out = codebook[idx]
// Replica invariants (DO NOT BREAK):
//  - dot: single sequential fp32 FMA chain per (n,k), d ascending.
//  - q = (S - 2*acc) + cn : two fp32 roundings in this order.
//  - S: fp32 squares, fp64-accumulated (order-invariant, R3-proven), 1 rounding.
//  - k ascending within thread (j, kg) + strict < ; cross-wave merge ascending
//    wave (= ascending k-range) tie-breaks on index.
//
// R7 (R6 post-mortem): R6's wave-uniform b-pointers were SCALARIZED by the
// compiler (s_load, VGPR=64 proves it) -> scalar pipe 4x oversubscribed,
// VALUBusy 24%. Geometry was right; the fix is forcing b through the VECTOR
// path: launder b-pointers through asm("" : "+v"(p)) so uniformity analysis
// fails -> global_load_dwordx4, 64-lane same-address = 1 L1 line broadcast.
// Also Jk=16 codes/thread: per dd-step/wave = 1 ds_read_b128 (0.375x FMA) +
// 16 L1 lines (0.5x) + 64 v_fmac (the saturated pipe).

#define D         256
#define K_TOTAL   1024
#define N_ROWS    32768
#define TM        64          // rows per block (lane = row; all 8 waves same rows)
#define XS_STRIDE 260         // 256+4: rows 16B-aligned; quad-stride 65 == 1 mod 8
                              // -> 64-lane b128 reads pack all banks evenly

// ---------------- kernel 1: codebook squared norms ----------------
__global__ void cnorm_kernel(const float* __restrict__ cb, float* __restrict__ cnorm) {
    const int wave = threadIdx.x >> 6;
    const int lane = threadIdx.x & 63;
    const int k    = blockIdx.x * 4 + wave;       // 0..1023
    float4 v = *(const float4*)(cb + (size_t)k * D + lane * 4);
    float sx = v.x * v.x, sy = v.y * v.y, sz = v.z * v.z, sw = v.w * v.w;
    double s = (double)sx + (double)sy + (double)sz + (double)sw;
    #pragma unroll
    for (int off = 32; off > 0; off >>= 1)
        s += __shfl_down(s, off, 64);
    if (lane == 0) cnorm[k] = (float)s;
}

// ---------------- kernel 2: fused distance + argmin + gather ----------------
__global__ __launch_bounds__(512, 4)
void vq_kernel(const float* __restrict__ x, const float* __restrict__ cb,
               const float* __restrict__ cnorm, float* __restrict__ out) {
    __shared__ float  xs[TM * XS_STRIDE];   // 66560 B x-tile [64 n][256 d]
    __shared__ double sred[TM][8];          // 4 KB row-norm partials

    const int tid  = threadIdx.x;
    const int lane = tid & 63;              // row owner
    const int wv   = tid >> 6;              // 0..7: k-range owner (128 codes each)
    const int n0   = blockIdx.x * TM;

    // ---- stage x-tile once (coalesced 16B loads, conflict-free writes) ----
    #pragma unroll
    for (int r = 0; r < 8; ++r) {
        const int idx  = tid + 512 * r;     // float4 index 0..4095
        const int row  = idx >> 6;
        const int col4 = idx & 63;
        float4 v = *(const float4*)(x + (size_t)(n0 + row) * D + col4 * 4);
        *(float4*)(xs + row * XS_STRIDE + col4 * 4) = v;
    }
    __syncthreads();

    // ---- row norms from LDS tile: fp32 squares, fp64 partials (8 thr/row) ----
    {
        const int r = tid >> 3, seg = tid & 7;
        const float* p = xs + r * XS_STRIDE + seg * 32;
        double s = 0.0;
        #pragma unroll
        for (int d = 0; d < 32; d += 4) {
            float4 v = *(const float4*)(p + d);
            float a0 = v.x * v.x, a1 = v.y * v.y, a2 = v.z * v.z, a3 = v.w * v.w;
            s += (double)a0 + (double)a1 + (double)a2 + (double)a3;
        }
        sred[r][seg] = s;
    }
    __syncthreads();

    float S;
    {
        double s = 0.0;
        #pragma unroll
        for (int t = 0; t < 8; ++t) s += sred[lane][t];
        S = (float)s;                       // single fp64->fp32 rounding
    }

    const float* arow = xs + lane * XS_STRIDE;
    float runmin = 1e30f;
    int   runidx = 0;

    // ---- K loop: 8 groups of 16 codes; b via VECTOR broadcast loads ----
    const int kbase = wv * 128;
    for (int kg = 0; kg < 8; ++kg) {
        const int k0 = kbase + kg * 16;     // ascending k across kg

        // Launder pointers through asm so the compiler cannot prove them
        // wave-uniform (R6: uniform -> s_load -> scalar pipe meltdown).
        // 4 base pointers, 4 rows each via immediate offsets (<= 4080 B).
        const float* bp0 = cb + (size_t)(k0 +  0) * D;
        const float* bp1 = cb + (size_t)(k0 +  4) * D;
        const float* bp2 = cb + (size_t)(k0 +  8) * D;
        const float* bp3 = cb + (size_t)(k0 + 12) * D;
        asm("" : "+v"(bp0), "+v"(bp1), "+v"(bp2), "+v"(bp3));

        float acc[16];
        #pragma unroll
        for (int j = 0; j < 16; ++j) acc[j] = 0.f;

        // Sequential fp32 FMA chain per (row, k), d ascending — fp32 replica.
        #pragma unroll 2
        for (int dd = 0; dd < D; dd += 4) {
            const float4 a = *(const float4*)(arow + dd);     // ds_read_b128
            float4 b[16];
            #pragma unroll
            for (int jj = 0; jj < 4; ++jj) {
                b[0  + jj] = *(const float4*)(bp0 + jj * D + dd);
                b[4  + jj] = *(const float4*)(bp1 + jj * D + dd);
                b[8  + jj] = *(const float4*)(bp2 + jj * D + dd);
                b[12 + jj] = *(const float4*)(bp3 + jj * D + dd);
            }
            #pragma unroll
            for (int j = 0; j < 16; ++j) {
                acc[j] += a.x * b[j].x;
                acc[j] += a.y * b[j].y;
                acc[j] += a.z * b[j].z;
                acc[j] += a.w * b[j].w;
            }
        }

        // q = (S - 2*acc) + cn, two fp32 roundings; j ascending = k ascending
        #pragma unroll
        for (int j = 0; j < 16; ++j) {
            const float cn = cnorm[k0 + j];
            const float t = S - 2.0f * acc[j];
            const float q = t + cn;
            if (q < runmin) { runmin = q; runidx = k0 + j; }
        }
    }

    // ---- cross-wave argmin merge (8 candidates/row), overlaid into dead xs ----
    __syncthreads();                        // all K-loop xs readers done
    float* red_val = xs;                    // [8][64]
    int*   red_idx = (int*)(xs + 512);      // [8][64]
    int*   best    = (int*)(xs + 1024);     // [64]
    red_val[wv * 64 + lane] = runmin;
    red_idx[wv * 64 + lane] = runidx;
    __syncthreads();
    if (tid < TM) {
        float bv = red_val[tid];
        int   bi = red_idx[tid];
        #pragma unroll
        for (int w = 1; w < 8; ++w) {       // ascending wave = ascending k-range
            const float v = red_val[w * 64 + tid];
            const int  ix = red_idx[w * 64 + tid];
            if (v < bv || (v == bv && ix < bi)) { bv = v; bi = ix; }
        }
        best[tid] = bi;
    }
    __syncthreads();

    // ---- gather winning codebook rows -> out, coalesced 16B ----
    #pragma unroll
    for (int r = 0; r < 8; ++r) {
        const int idx  = tid + 512 * r;
        const int row  = idx >> 6;
        const int col4 = idx & 63;
        const int k    = best[row];
        float4 v = *(const float4*)(cb + (size_t)k * D + col4 * 4);
        *(float4*)(out + (size_t)(n0 + row) * D + col4 * 4) = v;
    }
}

extern "C" void kernel_launch(void* const* d_in, const int* in_sizes, int n_in,
                              void* d_out, int out_size, void* d_ws, size_t ws_size,
                              hipStream_t stream) {
    const float* x  = (const float*)d_in[0];   // [32768, 256]
    const float* cb = (const float*)d_in[1];   // [1024, 256]
    float* out   = (float*)d_out;              // [32768, 256]
    float* cnorm = (float*)d_ws;               // 1024 fp32 scratch

    const int N = in_sizes[0] / D;             // 32768
    cnorm_kernel<<<K_TOTAL / 4, 256, 0, stream>>>(cb, cnorm);
    vq_kernel<<<N / TM, 512, 0, stream>>>(x, cb, cnorm, out);
}

// Round 8
// 374.210 us; speedup vs baseline: 2.7109x; 2.6976x over previous
//
#include <hip/hip_runtime.h>

// VectorQuantizer: x [32768, 256] fp32, codebook [1024, 256] fp32.
// Harness reference recomputes in float32 (R3: absmax==0 with fp32-replica):
//   d[n,k] = fl( fl( ||x_n||^2 - 2*dot(x_n,c_k) ) + ||c_k||^2 )  all fp32
//   idx = np.argmin (first-index ties), out = codebook[idx]
// Replica invariants (DO NOT BREAK):
//  - dot: single sequential fp32 FMA chain per (n,k), d ascending.
//  - q = (S - 2*acc) + cn : two fp32 roundings in this order.
//  - S: fp32 squares, fp64-accumulated (order-invariant, R3-proven), 1 rounding.
//  - k ascending within thread; cross-thread merge tie-breaks on index;
//    cross-half merge prefers half 0 (lower k) on ties.
//
// R8: R3 structure (b in LDS chunks, a from global broadcast) with In=8.
// Pipe law (measured): LDS/FMA = 6/In -> In=4 was 1.5x oversubscribed (R3),
// In=2 was 3x (R5). In=8 gives 0.75x, L1 0.5x, FMA the top pipe.
// In=8 forces TM=128; to keep >=2 blocks/CU the CODEBOOK IS SPLIT: each block
// scores 512 codes (half), emits per-row (min,idx) to ws; a merge+gather
// kernel combines halves. Grid 512, 2 blocks/CU, LDS 68.7 KB.
// R6/R7 lesson: never let b-addresses be wave-uniform (scalarization trap).

#define D         256
#define K_TOTAL   1024
#define N_ROWS    32768
#define TM        128         // rows per block
#define TN        64          // codes per LDS chunk
#define KHALF     512         // codes per block (half the codebook)
#define NCHUNK    (KHALF / TN)
#define CS_STRIDE 260         // 256+4: rows 16B-aligned; 16 tx-owners -> <=2-way (free)

// ---------------- kernel 1: codebook squared norms ----------------
__global__ void cnorm_kernel(const float* __restrict__ cb, float* __restrict__ cnorm) {
    const int wave = threadIdx.x >> 6;
    const int lane = threadIdx.x & 63;
    const int k    = blockIdx.x * 4 + wave;       // 0..1023
    float4 v = *(const float4*)(cb + (size_t)k * D + lane * 4);
    float sx = v.x * v.x, sy = v.y * v.y, sz = v.z * v.z, sw = v.w * v.w;
    double s = (double)sx + (double)sy + (double)sz + (double)sw;
    #pragma unroll
    for (int off = 32; off > 0; off >>= 1)
        s += __shfl_down(s, off, 64);
    if (lane == 0) cnorm[k] = (float)s;
}

// ---------------- kernel 2: half-codebook distance + per-row top1 ----------------
__global__ __launch_bounds__(256, 2)
void vq_kernel(const float* __restrict__ x, const float* __restrict__ cb,
               const float* __restrict__ cnorm,
               float* __restrict__ vout, int* __restrict__ iout) {
    __shared__ float  cs[TN * CS_STRIDE];   // 66560 B codebook chunk [64 k][256 d]
    __shared__ double sred[TM][2];          // 2 KB row-norm partials

    const int tid  = threadIdx.x;
    const int tx   = tid & 15;              // k-owner: k = k0 + tx + 16j, j<4
    const int ty   = tid >> 4;              // n-owner: rows ty + 16i, i<8
    const int half = blockIdx.x & 1;        // codebook half
    const int rb   = blockIdx.x >> 1;
    const int n0   = rb * TM;
    const int kbase = half * KHALF;

    // ---- in-block row norms: fp32 squares, fp64 partials (2 thr/row) ----
    {
        const int r = tid >> 1, seg = tid & 1;
        const float* p = x + (size_t)(n0 + r) * D + seg * 128;
        double s = 0.0;
        #pragma unroll
        for (int d = 0; d < 128; d += 4) {
            float4 v = *(const float4*)(p + d);
            float a0 = v.x * v.x, a1 = v.y * v.y, a2 = v.z * v.z, a3 = v.w * v.w;
            s += (double)a0 + (double)a1 + (double)a2 + (double)a3;
        }
        sred[r][seg] = s;
    }
    __syncthreads();

    float S[8];
    const float* arow[8];
    #pragma unroll
    for (int i = 0; i < 8; ++i) {
        const int rr = ty + 16 * i;
        S[i]    = (float)(sred[rr][0] + sred[rr][1]);   // single fp64->fp32 rounding
        arow[i] = x + (size_t)(n0 + rr) * D;
    }

    float runmin[8];
    int   runidx[8];
    #pragma unroll
    for (int i = 0; i < 8; ++i) { runmin[i] = 1e30f; runidx[i] = kbase; }

    for (int kc = 0; kc < NCHUNK; ++kc) {
        const int k0 = kbase + kc * TN;

        __syncthreads();   // protect cs from previous chunk's readers
        {   // stage 64 codebook rows: coalesced 16B loads, conflict-free writes
            #pragma unroll
            for (int r = 0; r < 16; ++r) {
                const int idx  = tid + 256 * r;      // float4 index 0..4095
                const int row  = idx >> 6;
                const int col4 = idx & 63;
                float4 v = *(const float4*)(cb + (size_t)(k0 + row) * D + col4 * 4);
                *(float4*)(cs + row * CS_STRIDE + col4 * 4) = v;
            }
        }
        __syncthreads();

        float acc[8][4];
        #pragma unroll
        for (int i = 0; i < 8; ++i)
            #pragma unroll
            for (int j = 0; j < 4; ++j) acc[i][j] = 0.f;

        // Sequential fp32 FMA chain per (i,j), d ascending — fp32 replica.
        // Per step/wave: 4 ds_read_b128 (0.75x FMA) + 8 global bcast (0.5x)
        // + 128 v_fmac (the saturated pipe).
        #pragma unroll 2
        for (int dd = 0; dd < D; dd += 4) {
            float4 b[4], a[8];
            #pragma unroll
            for (int j = 0; j < 4; ++j) b[j] = *(const float4*)(cs + (tx + 16 * j) * CS_STRIDE + dd);
            #pragma unroll
            for (int i = 0; i < 8; ++i) a[i] = *(const float4*)(arow[i] + dd);
            #pragma unroll
            for (int i = 0; i < 8; ++i)
                #pragma unroll
                for (int j = 0; j < 4; ++j) {
                    acc[i][j] += a[i].x * b[j].x;
                    acc[i][j] += a[i].y * b[j].y;
                    acc[i][j] += a[i].z * b[j].z;
                    acc[i][j] += a[i].w * b[j].w;
                }
        }

        // q = (S - 2*acc) + cn, two fp32 roundings; ascending j/kc = ascending k
        #pragma unroll
        for (int j = 0; j < 4; ++j) {
            const int k = k0 + tx + 16 * j;
            const float cn = cnorm[k];
            #pragma unroll
            for (int i = 0; i < 8; ++i) {
                const float t = S[i] - 2.0f * acc[i][j];
                const float q = t + cn;
                if (q < runmin[i]) { runmin[i] = q; runidx[i] = k; }
            }
        }
    }

    // ---- cross-tx argmin merge (16 candidates/row), overlaid into dead cs ----
    __syncthreads();                        // last chunk's cs readers done
    float* red_val = cs;                    // [128][16]
    int*   red_idx = (int*)(cs + 2048);     // [128][16]
    #pragma unroll
    for (int i = 0; i < 8; ++i) {
        const int row = ty + 16 * i;
        red_val[row * 16 + tx] = runmin[i];
        red_idx[row * 16 + tx] = runidx[i];
    }
    __syncthreads();
    if (tid < TM) {
        const int row = tid;
        float bv = red_val[row * 16];
        int   bi = red_idx[row * 16];
        #pragma unroll
        for (int t = 1; t < 16; ++t) {
            const float v = red_val[row * 16 + t];
            const int  ix = red_idx[row * 16 + t];
            if (v < bv || (v == bv && ix < bi)) { bv = v; bi = ix; }
        }
        vout[(size_t)half * N_ROWS + n0 + row] = bv;   // coalesced
        iout[(size_t)half * N_ROWS + n0 + row] = bi;
    }
}

// ---------------- kernel 3: merge halves + gather ----------------
__global__ __launch_bounds__(256)
void merge_kernel(const float* __restrict__ cb,
                  const float* __restrict__ vout, const int* __restrict__ iout,
                  float* __restrict__ out) {
    __shared__ int bi[64];
    const int tid = threadIdx.x;
    const int n0  = blockIdx.x * 64;
    if (tid < 64) {
        const int row = n0 + tid;
        const float v0 = vout[row], v1 = vout[N_ROWS + row];
        const int   i0 = iout[row], i1 = iout[N_ROWS + row];
        // half 0 holds lower k: ties -> half 0 = np first-index
        bi[tid] = (v1 < v0) ? i1 : i0;
    }
    __syncthreads();
    #pragma unroll
    for (int r = 0; r < 16; ++r) {
        const int idx  = tid + 256 * r;     // float4 index 0..4095
        const int row  = idx >> 6;
        const int col4 = idx & 63;
        const int k    = bi[row];
        float4 v = *(const float4*)(cb + (size_t)k * D + col4 * 4);
        *(float4*)(out + (size_t)(n0 + row) * D + col4 * 4) = v;
    }
}

extern "C" void kernel_launch(void* const* d_in, const int* in_sizes, int n_in,
                              void* d_out, int out_size, void* d_ws, size_t ws_size,
                              hipStream_t stream) {
    const float* x  = (const float*)d_in[0];   // [32768, 256]
    const float* cb = (const float*)d_in[1];   // [1024, 256]
    float* out = (float*)d_out;                // [32768, 256]

    // ws: cnorm 4 KB | vout 2*32768 f32 (256 KB) | iout 2*32768 i32 (256 KB)
    float* cnorm = (float*)d_ws;
    float* vout  = (float*)((char*)d_ws + 4096);
    int*   iout  = (int*)((char*)d_ws + 4096 + 2 * N_ROWS * 4);

    cnorm_kernel<<<K_TOTAL / 4, 256, 0, stream>>>(cb, cnorm);
    vq_kernel<<<(N_ROWS / TM) * 2, 256, 0, stream>>>(x, cb, cnorm, vout, iout);
    merge_kernel<<<N_ROWS / 64, 256, 0, stream>>>(cb, vout, iout, out);
}